// Round 14
// baseline (288.622 us; speedup 1.0000x reference)
//
#include <hip/hip_runtime.h>
#include <hip/hip_bf16.h>
#include <math.h>

// Problem constants (from reference)
#define U_N 2048
#define I_N 16384
#define F_N 64
#define H_N 32
#define KDIM 16384     // item dimension of A
#define NEGV (-1e30f)
#define NB_DEG 256     // partial-histogram blocks (1 per CU)

typedef __attribute__((ext_vector_type(4))) float f32x4;    // MFMA accumulator

// async global -> LDS, 16B per lane (wave-uniform LDS base + lane*16)
__device__ __forceinline__ void gload16(const void* g, void* l) {
    __builtin_amdgcn_global_load_lds(
        (const __attribute__((address_space(1))) unsigned int*)g,
        (__attribute__((address_space(3))) unsigned int*)l, 16, 0, 0);
}

// ---------------- per-block LDS degree histograms + zero C/out --------------
__global__ __launch_bounds__(256) void k_deg_part(const int* __restrict__ src,
                                                  const int* __restrict__ dst, int E,
                                                  unsigned int* __restrict__ pu,
                                                  unsigned int* __restrict__ pi2,
                                                  float* __restrict__ C,
                                                  float* __restrict__ out) {
    __shared__ unsigned int hu[U_N];        // 8 KB
    __shared__ unsigned int hi2[I_N / 2];   // 32 KB
    int tid = threadIdx.x;
    for (int t = tid; t < U_N; t += 256) hu[t] = 0u;
    for (int t = tid; t < I_N / 2; t += 256) hi2[t] = 0u;
    __syncthreads();
    const int4* s4 = (const int4*)src;
    const int4* d4 = (const int4*)dst;
    int nv = E >> 2;
    for (int v = blockIdx.x * 256 + tid; v < nv; v += NB_DEG * 256) {
        int4 u = s4[v], i = d4[v];
        atomicAdd(&hu[u.x], 1u); atomicAdd(&hi2[i.x >> 1], 1u << ((i.x & 1) * 16));
        atomicAdd(&hu[u.y], 1u); atomicAdd(&hi2[i.y >> 1], 1u << ((i.y & 1) * 16));
        atomicAdd(&hu[u.z], 1u); atomicAdd(&hi2[i.z >> 1], 1u << ((i.z & 1) * 16));
        atomicAdd(&hu[u.w], 1u); atomicAdd(&hi2[i.w >> 1], 1u << ((i.w & 1) * 16));
    }
    if (blockIdx.x == 0) {                  // tail edges (E % 4)
        int e = nv * 4 + tid;
        if (e < E) {
            atomicAdd(&hu[src[e]], 1u);
            int i = dst[e];
            atomicAdd(&hi2[i >> 1], 1u << ((i & 1) * 16));
        }
    }
    __syncthreads();
    unsigned int* pub = pu + (size_t)blockIdx.x * U_N;
    unsigned int* pib = pi2 + (size_t)blockIdx.x * (I_N / 2);
    for (int t = tid; t < U_N; t += 256) pub[t] = hu[t];
    for (int t = tid; t < I_N / 2; t += 256) pib[t] = hi2[t];
    // zero C and out (replaces two memset dispatches; idle BW here)
    const float4 z4 = {0.f, 0.f, 0.f, 0.f};
    float4* C4 = (float4*)C;
    for (int t = blockIdx.x * 256 + tid; t < U_N * U_N / 4; t += NB_DEG * 256)
        C4[t] = z4;
    float4* o4 = (float4*)out;
    for (int t = blockIdx.x * 256 + tid; t < (U_N * U_N + U_N) / 4; t += NB_DEG * 256)
        o4[t] = z4;
}

// ---------------- parallel partial reduce -> degrees/log1p/Dh ---------------
__global__ __launch_bounds__(256) void k_node2(const unsigned int* __restrict__ pu,
                                               const unsigned int* __restrict__ pi2,
                                               float* __restrict__ du,
                                               float* __restrict__ di,
                                               float* __restrict__ Dh,
                                               float* __restrict__ out_du,
                                               unsigned int* __restrict__ degu) {
    __shared__ unsigned int red[8][32];
    int j = threadIdx.x >> 5, l = threadIdx.x & 31;
    int e = blockIdx.x * 32 + l;
    unsigned int s = 0;
    if (e < U_N) {
        const unsigned int* p = pu + e;
#pragma unroll
        for (int k = 0; k < 32; ++k) s += p[(size_t)(j * 32 + k) * U_N];
    } else {
        const unsigned int* p = pi2 + (e - U_N);
#pragma unroll
        for (int k = 0; k < 32; ++k) s += p[(size_t)(j * 32 + k) * (I_N / 2)];
    }
    red[j][l] = s;
    __syncthreads();
    if (threadIdx.x < 32) {
        unsigned int t = 0;
#pragma unroll
        for (int jj = 0; jj < 8; ++jj) t += red[jj][l];
        if (e < U_N) {
            degu[e] = t;
            float v = log1pf((float)t);
            du[e] = v;
            Dh[e] = sqrtf(v);
            out_du[e] = v;   // second output of the reference
        } else {
            int ii = e - U_N;
            di[2 * ii]     = log1pf((float)(t & 0xffffu));
            di[2 * ii + 1] = log1pf((float)(t >> 16));
        }
    }
}

// ---------------- base (hierarchical scan) + chunk-parallel cursors ---------
__global__ __launch_bounds__(256) void k_pof(const unsigned int* __restrict__ pu,
                                             const unsigned int* __restrict__ degu,
                                             unsigned int* __restrict__ base,
                                             unsigned int* __restrict__ pof) {
    __shared__ unsigned int dg[U_N];    // degrees -> exclusive base
    __shared__ unsigned int wt[4];
    __shared__ unsigned int ps[8][32];
    int tid = threadIdx.x;
    int wave = tid >> 6, lane = tid & 63;
    for (int t = tid; t < U_N; t += 256) dg[t] = degu[t];
    __syncthreads();
    unsigned int loc[8];
    unsigned int s = 0;
#pragma unroll
    for (int j = 0; j < 8; ++j) { loc[j] = dg[tid * 8 + j]; s += loc[j]; }
    unsigned int inc = s;
#pragma unroll
    for (int off = 1; off < 64; off <<= 1) {
        unsigned int o = __shfl_up(inc, off);
        if (lane >= off) inc += o;
    }
    if (lane == 63) wt[wave] = inc;
    __syncthreads();
    unsigned int woff = 0;
#pragma unroll
    for (int w = 0; w < 4; ++w) woff += (w < wave) ? wt[w] : 0u;
    unsigned int ex = woff + inc - s;
    __syncthreads();
    {
        unsigned int run = ex;
#pragma unroll
        for (int j = 0; j < 8; ++j) { unsigned int v = loc[j]; dg[tid * 8 + j] = run; run += v; }
    }
    __syncthreads();
    int c = tid >> 5, l = tid & 31;
    int u = blockIdx.x * 32 + l;
    if (c == 0) base[u] = dg[u];
    unsigned int v32[32];
    unsigned int sum = 0;
#pragma unroll
    for (int k = 0; k < 32; ++k) {
        v32[k] = pu[(size_t)(c * 32 + k) * U_N + u];
        sum += v32[k];
    }
    ps[c][l] = sum;
    __syncthreads();
    unsigned int run = dg[u];
#pragma unroll
    for (int c2 = 0; c2 < 8; ++c2) run += (c2 < c) ? ps[c2][l] : 0u;
#pragma unroll
    for (int k = 0; k < 32; ++k) {
        pof[(size_t)(c * 32 + k) * U_N + u] = run;
        run += v32[k];
    }
}

// ---------------- fused: esort (blocks 0-255) | projections (blocks 256+) ---
// esort traversal must match k_deg_part exactly (same block/stride/tail map).
#define NPROJ (((U_N + I_N) * H_N) / 256)   // 2304 proj blocks
__global__ __launch_bounds__(256) void k_pe(const int* __restrict__ src,
                                            const int* __restrict__ dst, int E,
                                            const unsigned int* __restrict__ pof,
                                            unsigned short* __restrict__ sorted,
                                            const float* __restrict__ x,
                                            const float* __restrict__ w1,
                                            const float* __restrict__ b1,
                                            const float* __restrict__ du,
                                            const float* __restrict__ di,
                                            float* __restrict__ Pu,
                                            float* __restrict__ Pi) {
    __shared__ unsigned int cur[U_N];   // 8 KB (esort blocks only)
    int tid = threadIdx.x;
    int bid = blockIdx.x;
    if (bid < NB_DEG) {
        const unsigned int* p = pof + (size_t)bid * U_N;
        for (int t = tid; t < U_N; t += 256) cur[t] = p[t];
        __syncthreads();
        const int4* s4 = (const int4*)src;
        const int4* d4 = (const int4*)dst;
        int nv = E >> 2;
        for (int v = bid * 256 + tid; v < nv; v += NB_DEG * 256) {
            int4 u = s4[v], i = d4[v];
            sorted[atomicAdd(&cur[u.x], 1u)] = (unsigned short)i.x;
            sorted[atomicAdd(&cur[u.y], 1u)] = (unsigned short)i.y;
            sorted[atomicAdd(&cur[u.z], 1u)] = (unsigned short)i.z;
            sorted[atomicAdd(&cur[u.w], 1u)] = (unsigned short)i.w;
        }
        if (bid == 0) {
            int e = nv * 4 + tid;
            if (e < E)
                sorted[atomicAdd(&cur[src[e]], 1u)] = (unsigned short)dst[e];
        }
    } else {
        int t = (bid - NB_DEG) * 256 + tid;
        if (t < U_N * H_N) {
            int u = t >> 5, j = t & 31;
            const float* xr = x + (size_t)u * F_N;
            const float* wr = w1 + (size_t)j * (2 * F_N + 2);
            float acc = b1[j] + du[u] * wr[64];
#pragma unroll
            for (int f = 0; f < F_N; ++f) acc = fmaf(xr[f], wr[f], acc);
            Pu[t] = acc;
        } else {
            int t2 = t - U_N * H_N;
            int i = t2 >> 5, j = t2 & 31;
            const float* xr = x + (size_t)(U_N + i) * F_N;
            const float* wr = w1 + (size_t)j * (2 * F_N + 2) + 65;
            float acc = di[i] * wr[64];  // w1[j][129]
#pragma unroll
            for (int f = 0; f < F_N; ++f) acc = fmaf(xr[f], wr[f], acc);
            Pi[t2] = acc;
        }
    }
}

// ---------------- per-user: weights + f32 LDS row -> fp8 row + exact diag ---
__global__ __launch_bounds__(256) void k_edge2(const unsigned short* __restrict__ sorted,
                                               const unsigned int* __restrict__ base,
                                               const unsigned int* __restrict__ degu,
                                               const float* __restrict__ Pu,
                                               const float* __restrict__ Pi,
                                               const float* __restrict__ w2,
                                               const float* __restrict__ b2,
                                               unsigned int* __restrict__ A8w,
                                               float* __restrict__ diag) {
    __shared__ float hrow[I_N];   // 64 KB
    __shared__ float red[256];
    int u = blockIdx.x, tid = threadIdx.x;
    float4* h4 = (float4*)hrow;
    float4 z4 = {0.f, 0.f, 0.f, 0.f};
#pragma unroll
    for (int j = 0; j < 16; ++j) h4[tid + j * 256] = z4;

    float pur[H_N], w2r[H_N];
#pragma unroll
    for (int j = 0; j < H_N; ++j) pur[j] = Pu[(size_t)u * H_N + j];
#pragma unroll
    for (int j = 0; j < H_N; ++j) w2r[j] = w2[j];
    float bb = b2[0];
    __syncthreads();

    int nb = (int)base[u], d = (int)degu[u];
    for (int k = tid; k < d; k += 256) {
        int i = (int)sorted[nb + k];
        const float4* pi4 = (const float4*)(Pi + (size_t)i * H_N);
        float acc = bb;
#pragma unroll
        for (int q = 0; q < H_N / 4; ++q) {
            float4 b = pi4[q];
            acc = fmaf(fmaxf(pur[4 * q + 0] + b.x, 0.f), w2r[4 * q + 0], acc);
            acc = fmaf(fmaxf(pur[4 * q + 1] + b.y, 0.f), w2r[4 * q + 1], acc);
            acc = fmaf(fmaxf(pur[4 * q + 2] + b.z, 0.f), w2r[4 * q + 2], acc);
            acc = fmaf(fmaxf(pur[4 * q + 3] + b.w, 0.f), w2r[4 * q + 3], acc);
        }
        float wgt = 1.0f / (1.0f + expf(-acc));
        atomicAdd(&hrow[i], wgt);   // ds_add_f32
    }
    __syncthreads();

    // flush fp8 row (4 vals/word, RNE) + exact fp32 sum of squares (diagonal)
    unsigned int* row = A8w + (size_t)u * (I_N / 4);
    float ss = 0.f;
#pragma unroll
    for (int j = 0; j < 16; ++j) {
        int w = tid + j * 256;
        float4 a = h4[w];
        int v = __builtin_amdgcn_cvt_pk_fp8_f32(a.x, a.y, 0, false);
        v = __builtin_amdgcn_cvt_pk_fp8_f32(a.z, a.w, v, true);
        row[w] = (unsigned int)v;
        ss = fmaf(a.x, a.x, ss); ss = fmaf(a.y, a.y, ss);
        ss = fmaf(a.z, a.z, ss); ss = fmaf(a.w, a.w, ss);
    }
    red[tid] = ss;
    __syncthreads();
#pragma unroll
    for (int s = 128; s > 0; s >>= 1) {
        if (tid < s) red[tid] += red[tid + s];
        __syncthreads();
    }
    if (tid == 0) diag[u] = red[0];
}

// ---------------- C = A * A^T via fp8 MFMA, XOR-swizzled LDS, XCD chunks ----
// KSPLIT=8: 1088 blocks ~4.25 resident/CU (32 KB LDS allows 5) -> overlap of
// the serial load->drain->MFMA chains, which bound the KSPLIT=4 variant.
#define BM 128
#define BKB 128                         // fp8 bytes per k-tile
#define NBLK (U_N / BM)                 // 16
#define NPAIR (NBLK * (NBLK + 1) / 2)   // 136
#define KSPLIT 8
#define KCH (KDIM / KSPLIT)             // 2048

__global__ __launch_bounds__(256) void k_syrk(const unsigned char* __restrict__ A8,
                                              float* __restrict__ C) {
    __shared__ unsigned char As[BM * BKB];   // 16 KB
    __shared__ unsigned char Bs[BM * BKB];   // 16 KB

    int k0 = blockIdx.x * KCH;          // k-chunk (XCD-locality)
    int p = blockIdx.y;                 // pair index -> (bi, bj), bi <= bj
    int bi = 0, rem = p;
    while (rem >= NBLK - bi) { rem -= NBLK - bi; ++bi; }
    int bj = bi + rem;
    int diagp = (bi == bj);

    int tid = threadIdx.x;
    int wave = tid >> 6, lane = tid & 63;

    // staging: wave w fills rows [w*32,w*32+32), 4 calls of 8 rows each.
    // lane l -> LDS (row l>>3, chunk pos l&7); global chunk = (l&7)^(l>>3).
    int srow = wave * 32 + (lane >> 3);
    int scol = ((lane & 7) ^ (lane >> 3)) * 16;   // bytes
    const unsigned char* Ag = A8 + (size_t)(bi * BM + srow) * KDIM + k0 + scol;
    const unsigned char* Bg = A8 + (size_t)(bj * BM + srow) * KDIM + k0 + scol;
    unsigned char* lA = As + (wave * 32) * BKB;   // wave-uniform bases
    unsigned char* lB = Bs + (wave * 32) * BKB;

    // MFMA coords: 4 waves, each a 64x64 quadrant (4x4 of 16x16 tiles)
    int wm = wave >> 1, wn = wave & 1;
    int lm = lane & 15, lq = lane >> 4;
    int lm7 = lm & 7;
    const unsigned char* bTile = diagp ? As : Bs;

    f32x4 acc[4][4];
#pragma unroll
    for (int m = 0; m < 4; ++m)
#pragma unroll
        for (int n = 0; n < 4; ++n) acc[m][n] = (f32x4){0.f, 0.f, 0.f, 0.f};

    for (int kt = 0; kt < KCH; kt += BKB) {
        __syncthreads();              // previous tile fully consumed
#pragma unroll
        for (int j = 0; j < 4; ++j)
            gload16(Ag + kt + (size_t)(j * 8) * KDIM, lA + j * 8 * BKB);
        if (!diagp) {
#pragma unroll
            for (int j = 0; j < 4; ++j)
                gload16(Bg + kt + (size_t)(j * 8) * KDIM, lB + j * 8 * BKB);
        }
        __syncthreads();              // vmcnt(0) drain -> tile ready

#pragma unroll
        for (int s = 0; s < 4; ++s) {   // 4 k-steps of 32 within BKB=128
            // canonical chunk c = s*2 + (lq>>1); half = lq&1
            int off = ((s * 2 + (lq >> 1)) ^ lm7) * 16 + (lq & 1) * 8;
            long av[4], bv[4];
#pragma unroll
            for (int m = 0; m < 4; ++m)
                av[m] = *(const long*)(As + (wm * 64 + m * 16 + lm) * BKB + off);
#pragma unroll
            for (int n = 0; n < 4; ++n)
                bv[n] = *(const long*)(bTile + (wn * 64 + n * 16 + lm) * BKB + off);
#pragma unroll
            for (int m = 0; m < 4; ++m)
#pragma unroll
                for (int n = 0; n < 4; ++n)
                    acc[m][n] = __builtin_amdgcn_mfma_f32_16x16x32_fp8_fp8(
                        av[m], bv[n], acc[m][n], 0, 0, 0);
        }
    }

    // epilogue: C/D layout col=lane&15, row=lq*4+reg (m89-verified).
    // Upper-triangle tile only; k_mirror fills the lower triangle.
#pragma unroll
    for (int m = 0; m < 4; ++m) {
        int rb = bi * BM + wm * 64 + m * 16 + lq * 4;
#pragma unroll
        for (int n = 0; n < 4; ++n) {
            int c = bj * BM + wn * 64 + n * 16 + lm;
            f32x4 v = acc[m][n];
#pragma unroll
            for (int g = 0; g < 4; ++g)
                atomicAdd(&C[(size_t)(rb + g) * U_N + c], v[g]);
        }
    }
}

// ---------------- mirror lower triangle from upper ----------------
__global__ __launch_bounds__(256) void k_mirror(float* __restrict__ C) {
    __shared__ float T[64][65];
    int tr = blockIdx.x, tc = blockIdx.y;   // dest 64-tile coords
    if ((tr >> 1) <= (tc >> 1)) return;     // keep only 128-block lower
    int lane = threadIdx.x & 63;
    int w = threadIdx.x >> 6;               // 0..3
#pragma unroll
    for (int s = 0; s < 16; ++s) {
        int r = s * 4 + w;
        T[r][lane] = C[(size_t)(tc * 64 + r) * U_N + tr * 64 + lane];
    }
    __syncthreads();
#pragma unroll
    for (int s = 0; s < 16; ++s) {
        int r = s * 4 + w;
        C[(size_t)(tr * 64 + r) * U_N + tc * 64 + lane] = T[lane][r];
    }
}

// ---------------- top-3 per row (scaled, exact diag) + fused scatter --------
__device__ __forceinline__ bool better(float va, int ia, float vb, int ib) {
    return (va > vb) || (va == vb && ia < ib);
}
__device__ __forceinline__ void ins3(float v, int i, float& v0, int& i0,
                                     float& v1, int& i1, float& v2, int& i2) {
    if (better(v, i, v0, i0)) { v2 = v1; i2 = i1; v1 = v0; i1 = i0; v0 = v; i0 = i; }
    else if (better(v, i, v1, i1)) { v2 = v1; i2 = i1; v1 = v; i1 = i; }
    else if (better(v, i, v2, i2)) { v2 = v; i2 = i; }
}

__global__ __launch_bounds__(256) void k_topk(const float* __restrict__ C,
                                              const float* __restrict__ Dh,
                                              const float* __restrict__ diag,
                                              float* __restrict__ out) {
    int wave = threadIdx.x >> 6, lane = threadIdx.x & 63;
    int r = blockIdx.x * 4 + wave;                // one wave per row
    float dr = Dh[r];
    float dex = diag[r] * dr * dr;                // exact C[r,r]*d_u[r]
    float dval = (dex > 0.f) ? dex : NEGV;
    const float4* row = (const float4*)(C + (size_t)r * U_N);
    const float4* dh4 = (const float4*)Dh;
    float v0 = NEGV, v1 = NEGV, v2 = NEGV;
    int i0 = 0x7fffffff, i1 = 0x7fffffff, i2 = 0x7fffffff;
    int qr = r >> 2;
    for (int q = lane; q < U_N / 4; q += 64) {
        float4 cv = row[q];
        float4 dv = dh4[q];
        int c = q * 4;
        float x0 = (cv.x > 0.f) ? cv.x * dr * dv.x : NEGV;
        float x1 = (cv.y > 0.f) ? cv.y * dr * dv.y : NEGV;
        float x2 = (cv.z > 0.f) ? cv.z * dr * dv.z : NEGV;
        float x3 = (cv.w > 0.f) ? cv.w * dr * dv.w : NEGV;
        if (q == qr) {                       // substitute exact diagonal
            int j = r & 3;
            if (j == 0) x0 = dval; else if (j == 1) x1 = dval;
            else if (j == 2) x2 = dval; else x3 = dval;
        }
        if (better(x0, c + 0, v2, i2)) ins3(x0, c + 0, v0, i0, v1, i1, v2, i2);
        if (better(x1, c + 1, v2, i2)) ins3(x1, c + 1, v0, i0, v1, i1, v2, i2);
        if (better(x2, c + 2, v2, i2)) ins3(x2, c + 2, v0, i0, v1, i1, v2, i2);
        if (better(x3, c + 3, v2, i2)) ins3(x3, c + 3, v0, i0, v1, i1, v2, i2);
    }
#pragma unroll
    for (int off = 1; off < 64; off <<= 1) {
        float ov0 = __shfl_xor(v0, off), ov1 = __shfl_xor(v1, off), ov2 = __shfl_xor(v2, off);
        int oi0 = __shfl_xor(i0, off), oi1 = __shfl_xor(i1, off), oi2 = __shfl_xor(i2, off);
        ins3(ov0, oi0, v0, i0, v1, i1, v2, i2);
        ins3(ov1, oi1, v0, i0, v1, i1, v2, i2);
        ins3(ov2, oi2, v0, i0, v1, i1, v2, i2);
    }
    if (lane == 0) {                 // fused scatter: S = T + T^T
        float vs[3] = {v0, v1, v2};
        int is[3] = {i0, i1, i2};
#pragma unroll
        for (int k = 0; k < 3; ++k) {
            if (vs[k] > 0.f) {
                atomicAdd(&out[(size_t)r * U_N + is[k]], 0.5f * vs[k]);
                atomicAdd(&out[(size_t)is[k] * U_N + r], 0.5f * vs[k]);
            }
        }
    }
}

extern "C" void kernel_launch(void* const* d_in, const int* in_sizes, int n_in,
                              void* d_out, int out_size, void* d_ws, size_t ws_size,
                              hipStream_t stream) {
    const float* x  = (const float*)d_in[0];
    const float* w1 = (const float*)d_in[1];
    const float* b1 = (const float*)d_in[2];
    const float* w2 = (const float*)d_in[3];
    const float* b2 = (const float*)d_in[4];
    const int* esrc = (const int*)d_in[5];
    const int* edst = (const int*)d_in[6];
    int E = in_sizes[5];
    float* out = (float*)d_out;

    // workspace layout (~65 MB)
    unsigned char* A8 = (unsigned char*)d_ws;             // U*I fp8 (32 MiB)
    float* C    = (float*)(A8 + (size_t)U_N * I_N);       // U*U (16 MiB)
    float* Pu   = C + (size_t)U_N * U_N;                  // U*H
    float* Pi   = Pu + (size_t)U_N * H_N;                 // I*H (2 MiB)
    unsigned int* pu  = (unsigned int*)(Pi + (size_t)I_N * H_N);  // NB*U (2 MiB)
    unsigned int* pi2 = pu + (size_t)NB_DEG * U_N;        // NB*I/2 (8 MiB)
    unsigned int* pof = pi2 + (size_t)NB_DEG * (I_N / 2); // NB*U (2 MiB)
    unsigned int* degu = pof + (size_t)NB_DEG * U_N;      // U
    unsigned int* base = degu + U_N;                      // U
    float* du   = (float*)(base + U_N);                   // U
    float* di   = du + U_N;                               // I
    float* Dh   = di + I_N;                               // U
    float* diag = Dh + U_N;                               // U
    unsigned short* sorted = (unsigned short*)(diag + U_N);   // E u16 (2 MiB)

    k_deg_part<<<NB_DEG, 256, 0, stream>>>(esrc, edst, E, pu, pi2, C, out);
    k_node2<<<(U_N + I_N / 2) / 32, 256, 0, stream>>>(pu, pi2, du, di, Dh,
                                                      out + (size_t)U_N * U_N, degu);
    k_pof<<<U_N / 32, 256, 0, stream>>>(pu, degu, base, pof);
    k_pe<<<NB_DEG + NPROJ, 256, 0, stream>>>(esrc, edst, E, pof, sorted,
                                             x, w1, b1, du, di, Pu, Pi);
    k_edge2<<<U_N, 256, 0, stream>>>(sorted, base, degu, Pu, Pi, w2, b2,
                                     (unsigned int*)A8, diag);
    k_syrk<<<dim3(KSPLIT, NPAIR), 256, 0, stream>>>(A8, C);
    k_mirror<<<dim3(U_N / 64, U_N / 64), 256, 0, stream>>>(C);
    k_topk<<<U_N / 4, 256, 0, stream>>>(C, Dh, diag, out);
}

// Round 15
// 288.270 us; speedup vs baseline: 1.0012x; 1.0012x over previous
//
#include <hip/hip_runtime.h>
#include <hip/hip_bf16.h>
#include <math.h>

// Problem constants (from reference)
#define U_N 2048
#define I_N 16384
#define F_N 64
#define H_N 32
#define KDIM 16384     // item dimension of A
#define NEGV (-1e30f)
#define NB_DEG 256     // partial-histogram blocks (1 per CU)

typedef __attribute__((ext_vector_type(4))) float f32x4;    // MFMA accumulator

// async global -> LDS, 16B per lane (wave-uniform LDS base + lane*16)
__device__ __forceinline__ void gload16(const void* g, void* l) {
    __builtin_amdgcn_global_load_lds(
        (const __attribute__((address_space(1))) unsigned int*)g,
        (__attribute__((address_space(3))) unsigned int*)l, 16, 0, 0);
}

// ---------------- per-block LDS degree histograms + zero C/out --------------
__global__ __launch_bounds__(256) void k_deg_part(const int* __restrict__ src,
                                                  const int* __restrict__ dst, int E,
                                                  unsigned int* __restrict__ pu,
                                                  unsigned int* __restrict__ pi2,
                                                  float* __restrict__ C,
                                                  float* __restrict__ out) {
    __shared__ unsigned int hu[U_N];        // 8 KB
    __shared__ unsigned int hi2[I_N / 2];   // 32 KB
    int tid = threadIdx.x;
    for (int t = tid; t < U_N; t += 256) hu[t] = 0u;
    for (int t = tid; t < I_N / 2; t += 256) hi2[t] = 0u;
    __syncthreads();
    const int4* s4 = (const int4*)src;
    const int4* d4 = (const int4*)dst;
    int nv = E >> 2;
    for (int v = blockIdx.x * 256 + tid; v < nv; v += NB_DEG * 256) {
        int4 u = s4[v], i = d4[v];
        atomicAdd(&hu[u.x], 1u); atomicAdd(&hi2[i.x >> 1], 1u << ((i.x & 1) * 16));
        atomicAdd(&hu[u.y], 1u); atomicAdd(&hi2[i.y >> 1], 1u << ((i.y & 1) * 16));
        atomicAdd(&hu[u.z], 1u); atomicAdd(&hi2[i.z >> 1], 1u << ((i.z & 1) * 16));
        atomicAdd(&hu[u.w], 1u); atomicAdd(&hi2[i.w >> 1], 1u << ((i.w & 1) * 16));
    }
    if (blockIdx.x == 0) {                  // tail edges (E % 4)
        int e = nv * 4 + tid;
        if (e < E) {
            atomicAdd(&hu[src[e]], 1u);
            int i = dst[e];
            atomicAdd(&hi2[i >> 1], 1u << ((i & 1) * 16));
        }
    }
    __syncthreads();
    unsigned int* pub = pu + (size_t)blockIdx.x * U_N;
    unsigned int* pib = pi2 + (size_t)blockIdx.x * (I_N / 2);
    for (int t = tid; t < U_N; t += 256) pub[t] = hu[t];
    for (int t = tid; t < I_N / 2; t += 256) pib[t] = hi2[t];
    // zero C and out (replaces two memset dispatches; idle BW here)
    const float4 z4 = {0.f, 0.f, 0.f, 0.f};
    float4* C4 = (float4*)C;
    for (int t = blockIdx.x * 256 + tid; t < U_N * U_N / 4; t += NB_DEG * 256)
        C4[t] = z4;
    float4* o4 = (float4*)out;
    for (int t = blockIdx.x * 256 + tid; t < (U_N * U_N + U_N) / 4; t += NB_DEG * 256)
        o4[t] = z4;
}

// ---------------- parallel partial reduce -> degrees/log1p/Dh ---------------
__global__ __launch_bounds__(256) void k_node2(const unsigned int* __restrict__ pu,
                                               const unsigned int* __restrict__ pi2,
                                               float* __restrict__ du,
                                               float* __restrict__ di,
                                               float* __restrict__ Dh,
                                               float* __restrict__ out_du,
                                               unsigned int* __restrict__ degu) {
    __shared__ unsigned int red[8][32];
    int j = threadIdx.x >> 5, l = threadIdx.x & 31;
    int e = blockIdx.x * 32 + l;
    unsigned int s = 0;
    if (e < U_N) {
        const unsigned int* p = pu + e;
#pragma unroll
        for (int k = 0; k < 32; ++k) s += p[(size_t)(j * 32 + k) * U_N];
    } else {
        const unsigned int* p = pi2 + (e - U_N);
#pragma unroll
        for (int k = 0; k < 32; ++k) s += p[(size_t)(j * 32 + k) * (I_N / 2)];
    }
    red[j][l] = s;
    __syncthreads();
    if (threadIdx.x < 32) {
        unsigned int t = 0;
#pragma unroll
        for (int jj = 0; jj < 8; ++jj) t += red[jj][l];
        if (e < U_N) {
            degu[e] = t;
            float v = log1pf((float)t);
            du[e] = v;
            Dh[e] = sqrtf(v);
            out_du[e] = v;   // second output of the reference
        } else {
            int ii = e - U_N;
            di[2 * ii]     = log1pf((float)(t & 0xffffu));
            di[2 * ii + 1] = log1pf((float)(t >> 16));
        }
    }
}

// ---------------- base (hierarchical scan) + chunk-parallel cursors ---------
__global__ __launch_bounds__(256) void k_pof(const unsigned int* __restrict__ pu,
                                             const unsigned int* __restrict__ degu,
                                             unsigned int* __restrict__ base,
                                             unsigned int* __restrict__ pof) {
    __shared__ unsigned int dg[U_N];    // degrees -> exclusive base
    __shared__ unsigned int wt[4];
    __shared__ unsigned int ps[8][32];
    int tid = threadIdx.x;
    int wave = tid >> 6, lane = tid & 63;
    for (int t = tid; t < U_N; t += 256) dg[t] = degu[t];
    __syncthreads();
    unsigned int loc[8];
    unsigned int s = 0;
#pragma unroll
    for (int j = 0; j < 8; ++j) { loc[j] = dg[tid * 8 + j]; s += loc[j]; }
    unsigned int inc = s;
#pragma unroll
    for (int off = 1; off < 64; off <<= 1) {
        unsigned int o = __shfl_up(inc, off);
        if (lane >= off) inc += o;
    }
    if (lane == 63) wt[wave] = inc;
    __syncthreads();
    unsigned int woff = 0;
#pragma unroll
    for (int w = 0; w < 4; ++w) woff += (w < wave) ? wt[w] : 0u;
    unsigned int ex = woff + inc - s;
    __syncthreads();
    {
        unsigned int run = ex;
#pragma unroll
        for (int j = 0; j < 8; ++j) { unsigned int v = loc[j]; dg[tid * 8 + j] = run; run += v; }
    }
    __syncthreads();
    int c = tid >> 5, l = tid & 31;
    int u = blockIdx.x * 32 + l;
    if (c == 0) base[u] = dg[u];
    unsigned int v32[32];
    unsigned int sum = 0;
#pragma unroll
    for (int k = 0; k < 32; ++k) {
        v32[k] = pu[(size_t)(c * 32 + k) * U_N + u];
        sum += v32[k];
    }
    ps[c][l] = sum;
    __syncthreads();
    unsigned int run = dg[u];
#pragma unroll
    for (int c2 = 0; c2 < 8; ++c2) run += (c2 < c) ? ps[c2][l] : 0u;
#pragma unroll
    for (int k = 0; k < 32; ++k) {
        pof[(size_t)(c * 32 + k) * U_N + u] = run;
        run += v32[k];
    }
}

// ---------------- fused: esort (blocks 0-255) | projections (blocks 256+) ---
// esort traversal must match k_deg_part exactly (same block/stride/tail map).
#define NPROJ (((U_N + I_N) * H_N) / 256)   // 2304 proj blocks
__global__ __launch_bounds__(256) void k_pe(const int* __restrict__ src,
                                            const int* __restrict__ dst, int E,
                                            const unsigned int* __restrict__ pof,
                                            unsigned short* __restrict__ sorted,
                                            const float* __restrict__ x,
                                            const float* __restrict__ w1,
                                            const float* __restrict__ b1,
                                            const float* __restrict__ du,
                                            const float* __restrict__ di,
                                            float* __restrict__ Pu,
                                            float* __restrict__ Pi) {
    __shared__ unsigned int cur[U_N];   // 8 KB (esort blocks only)
    int tid = threadIdx.x;
    int bid = blockIdx.x;
    if (bid < NB_DEG) {
        const unsigned int* p = pof + (size_t)bid * U_N;
        for (int t = tid; t < U_N; t += 256) cur[t] = p[t];
        __syncthreads();
        const int4* s4 = (const int4*)src;
        const int4* d4 = (const int4*)dst;
        int nv = E >> 2;
        for (int v = bid * 256 + tid; v < nv; v += NB_DEG * 256) {
            int4 u = s4[v], i = d4[v];
            sorted[atomicAdd(&cur[u.x], 1u)] = (unsigned short)i.x;
            sorted[atomicAdd(&cur[u.y], 1u)] = (unsigned short)i.y;
            sorted[atomicAdd(&cur[u.z], 1u)] = (unsigned short)i.z;
            sorted[atomicAdd(&cur[u.w], 1u)] = (unsigned short)i.w;
        }
        if (bid == 0) {
            int e = nv * 4 + tid;
            if (e < E)
                sorted[atomicAdd(&cur[src[e]], 1u)] = (unsigned short)dst[e];
        }
    } else {
        int t = (bid - NB_DEG) * 256 + tid;
        if (t < U_N * H_N) {
            int u = t >> 5, j = t & 31;
            const float* xr = x + (size_t)u * F_N;
            const float* wr = w1 + (size_t)j * (2 * F_N + 2);
            float acc = b1[j] + du[u] * wr[64];
#pragma unroll
            for (int f = 0; f < F_N; ++f) acc = fmaf(xr[f], wr[f], acc);
            Pu[t] = acc;
        } else {
            int t2 = t - U_N * H_N;
            int i = t2 >> 5, j = t2 & 31;
            const float* xr = x + (size_t)(U_N + i) * F_N;
            const float* wr = w1 + (size_t)j * (2 * F_N + 2) + 65;
            float acc = di[i] * wr[64];  // w1[j][129]
#pragma unroll
            for (int f = 0; f < F_N; ++f) acc = fmaf(xr[f], wr[f], acc);
            Pi[t2] = acc;
        }
    }
}

// ---------------- per-user: weights + f32 LDS row -> fp8 row + exact diag ---
__global__ __launch_bounds__(256) void k_edge2(const unsigned short* __restrict__ sorted,
                                               const unsigned int* __restrict__ base,
                                               const unsigned int* __restrict__ degu,
                                               const float* __restrict__ Pu,
                                               const float* __restrict__ Pi,
                                               const float* __restrict__ w2,
                                               const float* __restrict__ b2,
                                               unsigned int* __restrict__ A8w,
                                               float* __restrict__ diag) {
    __shared__ float hrow[I_N];   // 64 KB
    __shared__ float red[256];
    int u = blockIdx.x, tid = threadIdx.x;
    float4* h4 = (float4*)hrow;
    float4 z4 = {0.f, 0.f, 0.f, 0.f};
#pragma unroll
    for (int j = 0; j < 16; ++j) h4[tid + j * 256] = z4;

    float pur[H_N], w2r[H_N];
#pragma unroll
    for (int j = 0; j < H_N; ++j) pur[j] = Pu[(size_t)u * H_N + j];
#pragma unroll
    for (int j = 0; j < H_N; ++j) w2r[j] = w2[j];
    float bb = b2[0];
    __syncthreads();

    int nb = (int)base[u], d = (int)degu[u];
    for (int k = tid; k < d; k += 256) {
        int i = (int)sorted[nb + k];
        const float4* pi4 = (const float4*)(Pi + (size_t)i * H_N);
        float acc = bb;
#pragma unroll
        for (int q = 0; q < H_N / 4; ++q) {
            float4 b = pi4[q];
            acc = fmaf(fmaxf(pur[4 * q + 0] + b.x, 0.f), w2r[4 * q + 0], acc);
            acc = fmaf(fmaxf(pur[4 * q + 1] + b.y, 0.f), w2r[4 * q + 1], acc);
            acc = fmaf(fmaxf(pur[4 * q + 2] + b.z, 0.f), w2r[4 * q + 2], acc);
            acc = fmaf(fmaxf(pur[4 * q + 3] + b.w, 0.f), w2r[4 * q + 3], acc);
        }
        float wgt = 1.0f / (1.0f + expf(-acc));
        atomicAdd(&hrow[i], wgt);   // ds_add_f32
    }
    __syncthreads();

    // flush fp8 row (4 vals/word, RNE) + exact fp32 sum of squares (diagonal)
    unsigned int* row = A8w + (size_t)u * (I_N / 4);
    float ss = 0.f;
#pragma unroll
    for (int j = 0; j < 16; ++j) {
        int w = tid + j * 256;
        float4 a = h4[w];
        int v = __builtin_amdgcn_cvt_pk_fp8_f32(a.x, a.y, 0, false);
        v = __builtin_amdgcn_cvt_pk_fp8_f32(a.z, a.w, v, true);
        row[w] = (unsigned int)v;
        ss = fmaf(a.x, a.x, ss); ss = fmaf(a.y, a.y, ss);
        ss = fmaf(a.z, a.z, ss); ss = fmaf(a.w, a.w, ss);
    }
    red[tid] = ss;
    __syncthreads();
#pragma unroll
    for (int s = 128; s > 0; s >>= 1) {
        if (tid < s) red[tid] += red[tid + s];
        __syncthreads();
    }
    if (tid == 0) diag[u] = red[0];
}

// ---------------- C = A * A^T via fp8 MFMA, XOR-swizzled LDS, XCD chunks ----
// KSPLIT=4 (epilogue atomics measured 3x to dominate above this), BKB=256:
// 16 k-iters/block, 128 MFMA per barrier (was 64 per 2 barriers) -> halves
// the vmcnt(0)+barrier drain count that bounds the KSPLIT=4 88us variant.
// 64 KB LDS -> 2 blocks/CU cap == what the 544-block grid occupies anyway.
// Swizzle: row = 256 B; 16 B chunk c of row r stored at pos c ^ (r & 15).
#define BM 128
#define BKB 256                         // fp8 bytes per k-tile row
#define NBLK (U_N / BM)                 // 16
#define NPAIR (NBLK * (NBLK + 1) / 2)   // 136
#define KSPLIT 4
#define KCH (KDIM / KSPLIT)             // 4096

__global__ __launch_bounds__(256) void k_syrk(const unsigned char* __restrict__ A8,
                                              float* __restrict__ C) {
    __shared__ unsigned char As[BM * BKB];   // 32 KB
    __shared__ unsigned char Bs[BM * BKB];   // 32 KB

    int k0 = blockIdx.x * KCH;          // k-chunk (XCD-locality)
    int p = blockIdx.y;                 // pair index -> (bi, bj), bi <= bj
    int bi = 0, rem = p;
    while (rem >= NBLK - bi) { rem -= NBLK - bi; ++bi; }
    int bj = bi + rem;
    int diagp = (bi == bj);

    int tid = threadIdx.x;
    int wave = tid >> 6, lane = tid & 63;

    // staging: wave w fills rows [w*32,w*32+32), 8 calls of 4 rows each.
    // lane l -> LDS (row l>>4, chunk pos l&15); global chunk = (l&15)^(row&15).
    int r4 = lane >> 4, cp = lane & 15;
    const unsigned char* Ab = A8 + (size_t)(bi * BM + wave * 32 + r4) * KDIM + k0;
    const unsigned char* Bb = A8 + (size_t)(bj * BM + wave * 32 + r4) * KDIM + k0;
    unsigned char* lA = As + (wave * 32) * BKB;   // wave-uniform bases
    unsigned char* lB = Bs + (wave * 32) * BKB;

    // MFMA coords: 4 waves, each a 64x64 quadrant (4x4 of 16x16 tiles)
    int wm = wave >> 1, wn = wave & 1;
    int lm = lane & 15, lq = lane >> 4;
    const unsigned char* bTile = diagp ? As : Bs;

    f32x4 acc[4][4];
#pragma unroll
    for (int m = 0; m < 4; ++m)
#pragma unroll
        for (int n = 0; n < 4; ++n) acc[m][n] = (f32x4){0.f, 0.f, 0.f, 0.f};

    for (int kt = 0; kt < KCH; kt += BKB) {
        __syncthreads();              // previous tile fully consumed
#pragma unroll
        for (int j = 0; j < 8; ++j) {
            int gc = (cp ^ ((j * 4 + r4) & 15)) << 4;
            gload16(Ab + (size_t)(j * 4) * KDIM + kt + gc, lA + j * 4 * BKB);
        }
        if (!diagp) {
#pragma unroll
            for (int j = 0; j < 8; ++j) {
                int gc = (cp ^ ((j * 4 + r4) & 15)) << 4;
                gload16(Bb + (size_t)(j * 4) * KDIM + kt + gc, lB + j * 4 * BKB);
            }
        }
        __syncthreads();              // vmcnt(0) drain -> tile ready

#pragma unroll
        for (int s = 0; s < 8; ++s) {   // 8 k-steps of 32 within BKB=256
            // canonical chunk c = s*2 + (lq>>1); half = lq&1; pos = c ^ lm
            int off = ((s * 2 + (lq >> 1)) ^ lm) * 16 + (lq & 1) * 8;
            long av[4], bv[4];
#pragma unroll
            for (int m = 0; m < 4; ++m)
                av[m] = *(const long*)(As + (wm * 64 + m * 16 + lm) * BKB + off);
#pragma unroll
            for (int n = 0; n < 4; ++n)
                bv[n] = *(const long*)(bTile + (wn * 64 + n * 16 + lm) * BKB + off);
#pragma unroll
            for (int m = 0; m < 4; ++m)
#pragma unroll
                for (int n = 0; n < 4; ++n)
                    acc[m][n] = __builtin_amdgcn_mfma_f32_16x16x32_fp8_fp8(
                        av[m], bv[n], acc[m][n], 0, 0, 0);
        }
    }

    // epilogue: C/D layout col=lane&15, row=lq*4+reg (m89-verified).
    // Upper-triangle tile only; k_mirror fills the lower triangle.
#pragma unroll
    for (int m = 0; m < 4; ++m) {
        int rb = bi * BM + wm * 64 + m * 16 + lq * 4;
#pragma unroll
        for (int n = 0; n < 4; ++n) {
            int c = bj * BM + wn * 64 + n * 16 + lm;
            f32x4 v = acc[m][n];
#pragma unroll
            for (int g = 0; g < 4; ++g)
                atomicAdd(&C[(size_t)(rb + g) * U_N + c], v[g]);
        }
    }
}

// ---------------- mirror lower triangle from upper ----------------
__global__ __launch_bounds__(256) void k_mirror(float* __restrict__ C) {
    __shared__ float T[64][65];
    int tr = blockIdx.x, tc = blockIdx.y;   // dest 64-tile coords
    if ((tr >> 1) <= (tc >> 1)) return;     // keep only 128-block lower
    int lane = threadIdx.x & 63;
    int w = threadIdx.x >> 6;               // 0..3
#pragma unroll
    for (int s = 0; s < 16; ++s) {
        int r = s * 4 + w;
        T[r][lane] = C[(size_t)(tc * 64 + r) * U_N + tr * 64 + lane];
    }
    __syncthreads();
#pragma unroll
    for (int s = 0; s < 16; ++s) {
        int r = s * 4 + w;
        C[(size_t)(tr * 64 + r) * U_N + tc * 64 + lane] = T[lane][r];
    }
}

// ---------------- top-3 per row (scaled, exact diag) + fused scatter --------
__device__ __forceinline__ bool better(float va, int ia, float vb, int ib) {
    return (va > vb) || (va == vb && ia < ib);
}
__device__ __forceinline__ void ins3(float v, int i, float& v0, int& i0,
                                     float& v1, int& i1, float& v2, int& i2) {
    if (better(v, i, v0, i0)) { v2 = v1; i2 = i1; v1 = v0; i1 = i0; v0 = v; i0 = i; }
    else if (better(v, i, v1, i1)) { v2 = v1; i2 = i1; v1 = v; i1 = i; }
    else if (better(v, i, v2, i2)) { v2 = v; i2 = i; }
}

__global__ __launch_bounds__(256) void k_topk(const float* __restrict__ C,
                                              const float* __restrict__ Dh,
                                              const float* __restrict__ diag,
                                              float* __restrict__ out) {
    int wave = threadIdx.x >> 6, lane = threadIdx.x & 63;
    int r = blockIdx.x * 4 + wave;                // one wave per row
    float dr = Dh[r];
    float dex = diag[r] * dr * dr;                // exact C[r,r]*d_u[r]
    float dval = (dex > 0.f) ? dex : NEGV;
    const float4* row = (const float4*)(C + (size_t)r * U_N);
    const float4* dh4 = (const float4*)Dh;
    float v0 = NEGV, v1 = NEGV, v2 = NEGV;
    int i0 = 0x7fffffff, i1 = 0x7fffffff, i2 = 0x7fffffff;
    int qr = r >> 2;
    for (int q = lane; q < U_N / 4; q += 64) {
        float4 cv = row[q];
        float4 dv = dh4[q];
        int c = q * 4;
        float x0 = (cv.x > 0.f) ? cv.x * dr * dv.x : NEGV;
        float x1 = (cv.y > 0.f) ? cv.y * dr * dv.y : NEGV;
        float x2 = (cv.z > 0.f) ? cv.z * dr * dv.z : NEGV;
        float x3 = (cv.w > 0.f) ? cv.w * dr * dv.w : NEGV;
        if (q == qr) {                       // substitute exact diagonal
            int j = r & 3;
            if (j == 0) x0 = dval; else if (j == 1) x1 = dval;
            else if (j == 2) x2 = dval; else x3 = dval;
        }
        if (better(x0, c + 0, v2, i2)) ins3(x0, c + 0, v0, i0, v1, i1, v2, i2);
        if (better(x1, c + 1, v2, i2)) ins3(x1, c + 1, v0, i0, v1, i1, v2, i2);
        if (better(x2, c + 2, v2, i2)) ins3(x2, c + 2, v0, i0, v1, i1, v2, i2);
        if (better(x3, c + 3, v2, i2)) ins3(x3, c + 3, v0, i0, v1, i1, v2, i2);
    }
#pragma unroll
    for (int off = 1; off < 64; off <<= 1) {
        float ov0 = __shfl_xor(v0, off), ov1 = __shfl_xor(v1, off), ov2 = __shfl_xor(v2, off);
        int oi0 = __shfl_xor(i0, off), oi1 = __shfl_xor(i1, off), oi2 = __shfl_xor(i2, off);
        ins3(ov0, oi0, v0, i0, v1, i1, v2, i2);
        ins3(ov1, oi1, v0, i0, v1, i1, v2, i2);
        ins3(ov2, oi2, v0, i0, v1, i1, v2, i2);
    }
    if (lane == 0) {                 // fused scatter: S = T + T^T
        float vs[3] = {v0, v1, v2};
        int is[3] = {i0, i1, i2};
#pragma unroll
        for (int k = 0; k < 3; ++k) {
            if (vs[k] > 0.f) {
                atomicAdd(&out[(size_t)r * U_N + is[k]], 0.5f * vs[k]);
                atomicAdd(&out[(size_t)is[k] * U_N + r], 0.5f * vs[k]);
            }
        }
    }
}

extern "C" void kernel_launch(void* const* d_in, const int* in_sizes, int n_in,
                              void* d_out, int out_size, void* d_ws, size_t ws_size,
                              hipStream_t stream) {
    const float* x  = (const float*)d_in[0];
    const float* w1 = (const float*)d_in[1];
    const float* b1 = (const float*)d_in[2];
    const float* w2 = (const float*)d_in[3];
    const float* b2 = (const float*)d_in[4];
    const int* esrc = (const int*)d_in[5];
    const int* edst = (const int*)d_in[6];
    int E = in_sizes[5];
    float* out = (float*)d_out;

    // workspace layout (~65 MB)
    unsigned char* A8 = (unsigned char*)d_ws;             // U*I fp8 (32 MiB)
    float* C    = (float*)(A8 + (size_t)U_N * I_N);       // U*U (16 MiB)
    float* Pu   = C + (size_t)U_N * U_N;                  // U*H
    float* Pi   = Pu + (size_t)U_N * H_N;                 // I*H (2 MiB)
    unsigned int* pu  = (unsigned int*)(Pi + (size_t)I_N * H_N);  // NB*U (2 MiB)
    unsigned int* pi2 = pu + (size_t)NB_DEG * U_N;        // NB*I/2 (8 MiB)
    unsigned int* pof = pi2 + (size_t)NB_DEG * (I_N / 2); // NB*U (2 MiB)
    unsigned int* degu = pof + (size_t)NB_DEG * U_N;      // U
    unsigned int* base = degu + U_N;                      // U
    float* du   = (float*)(base + U_N);                   // U
    float* di   = du + U_N;                               // I
    float* Dh   = di + I_N;                               // U
    float* diag = Dh + U_N;                               // U
    unsigned short* sorted = (unsigned short*)(diag + U_N);   // E u16 (2 MiB)

    k_deg_part<<<NB_DEG, 256, 0, stream>>>(esrc, edst, E, pu, pi2, C, out);
    k_node2<<<(U_N + I_N / 2) / 32, 256, 0, stream>>>(pu, pi2, du, di, Dh,
                                                      out + (size_t)U_N * U_N, degu);
    k_pof<<<U_N / 32, 256, 0, stream>>>(pu, degu, base, pof);
    k_pe<<<NB_DEG + NPROJ, 256, 0, stream>>>(esrc, edst, E, pof, sorted,
                                             x, w1, b1, du, di, Pu, Pi);
    k_edge2<<<U_N, 256, 0, stream>>>(sorted, base, degu, Pu, Pi, w2, b2,
                                     (unsigned int*)A8, diag);
    k_syrk<<<dim3(KSPLIT, NPAIR), 256, 0, stream>>>(A8, C);
    k_mirror<<<dim3(U_N / 64, U_N / 64), 256, 0, stream>>>(C);
    k_topk<<<U_N / 4, 256, 0, stream>>>(C, Dh, diag, out);
}

// Round 16
// 283.345 us; speedup vs baseline: 1.0186x; 1.0174x over previous
//
#include <hip/hip_runtime.h>
#include <hip/hip_bf16.h>
#include <math.h>

// Problem constants (from reference)
#define U_N 2048
#define I_N 16384
#define F_N 64
#define H_N 32
#define KDIM 16384     // item dimension of A
#define NEGV (-1e30f)
#define NB_DEG 256     // partial-histogram blocks (1 per CU)

typedef __attribute__((ext_vector_type(4))) float f32x4;    // MFMA accumulator

// async global -> LDS, 16B per lane (wave-uniform LDS base + lane*16)
__device__ __forceinline__ void gload16(const void* g, void* l) {
    __builtin_amdgcn_global_load_lds(
        (const __attribute__((address_space(1))) unsigned int*)g,
        (__attribute__((address_space(3))) unsigned int*)l, 16, 0, 0);
}

// ---------------- per-block LDS degree histograms + zero C/out --------------
__global__ __launch_bounds__(256) void k_deg_part(const int* __restrict__ src,
                                                  const int* __restrict__ dst, int E,
                                                  unsigned int* __restrict__ pu,
                                                  unsigned int* __restrict__ pi2,
                                                  float* __restrict__ C,
                                                  float* __restrict__ out) {
    __shared__ unsigned int hu[U_N];        // 8 KB
    __shared__ unsigned int hi2[I_N / 2];   // 32 KB
    int tid = threadIdx.x;
    for (int t = tid; t < U_N; t += 256) hu[t] = 0u;
    for (int t = tid; t < I_N / 2; t += 256) hi2[t] = 0u;
    __syncthreads();
    const int4* s4 = (const int4*)src;
    const int4* d4 = (const int4*)dst;
    int nv = E >> 2;
    for (int v = blockIdx.x * 256 + tid; v < nv; v += NB_DEG * 256) {
        int4 u = s4[v], i = d4[v];
        atomicAdd(&hu[u.x], 1u); atomicAdd(&hi2[i.x >> 1], 1u << ((i.x & 1) * 16));
        atomicAdd(&hu[u.y], 1u); atomicAdd(&hi2[i.y >> 1], 1u << ((i.y & 1) * 16));
        atomicAdd(&hu[u.z], 1u); atomicAdd(&hi2[i.z >> 1], 1u << ((i.z & 1) * 16));
        atomicAdd(&hu[u.w], 1u); atomicAdd(&hi2[i.w >> 1], 1u << ((i.w & 1) * 16));
    }
    if (blockIdx.x == 0) {                  // tail edges (E % 4)
        int e = nv * 4 + tid;
        if (e < E) {
            atomicAdd(&hu[src[e]], 1u);
            int i = dst[e];
            atomicAdd(&hi2[i >> 1], 1u << ((i & 1) * 16));
        }
    }
    __syncthreads();
    unsigned int* pub = pu + (size_t)blockIdx.x * U_N;
    unsigned int* pib = pi2 + (size_t)blockIdx.x * (I_N / 2);
    for (int t = tid; t < U_N; t += 256) pub[t] = hu[t];
    for (int t = tid; t < I_N / 2; t += 256) pib[t] = hi2[t];
    // zero C and out (replaces two memset dispatches; idle BW here)
    const float4 z4 = {0.f, 0.f, 0.f, 0.f};
    float4* C4 = (float4*)C;
    for (int t = blockIdx.x * 256 + tid; t < U_N * U_N / 4; t += NB_DEG * 256)
        C4[t] = z4;
    float4* o4 = (float4*)out;
    for (int t = blockIdx.x * 256 + tid; t < (U_N * U_N + U_N) / 4; t += NB_DEG * 256)
        o4[t] = z4;
}

// ---------------- parallel partial reduce -> degrees/log1p/Dh ---------------
__global__ __launch_bounds__(256) void k_node2(const unsigned int* __restrict__ pu,
                                               const unsigned int* __restrict__ pi2,
                                               float* __restrict__ du,
                                               float* __restrict__ di,
                                               float* __restrict__ Dh,
                                               float* __restrict__ out_du,
                                               unsigned int* __restrict__ degu) {
    __shared__ unsigned int red[8][32];
    int j = threadIdx.x >> 5, l = threadIdx.x & 31;
    int e = blockIdx.x * 32 + l;
    unsigned int s = 0;
    if (e < U_N) {
        const unsigned int* p = pu + e;
#pragma unroll
        for (int k = 0; k < 32; ++k) s += p[(size_t)(j * 32 + k) * U_N];
    } else {
        const unsigned int* p = pi2 + (e - U_N);
#pragma unroll
        for (int k = 0; k < 32; ++k) s += p[(size_t)(j * 32 + k) * (I_N / 2)];
    }
    red[j][l] = s;
    __syncthreads();
    if (threadIdx.x < 32) {
        unsigned int t = 0;
#pragma unroll
        for (int jj = 0; jj < 8; ++jj) t += red[jj][l];
        if (e < U_N) {
            degu[e] = t;
            float v = log1pf((float)t);
            du[e] = v;
            Dh[e] = sqrtf(v);
            out_du[e] = v;   // second output of the reference
        } else {
            int ii = e - U_N;
            di[2 * ii]     = log1pf((float)(t & 0xffffu));
            di[2 * ii + 1] = log1pf((float)(t >> 16));
        }
    }
}

// ---------------- base (hierarchical scan) + chunk-parallel cursors ---------
__global__ __launch_bounds__(256) void k_pof(const unsigned int* __restrict__ pu,
                                             const unsigned int* __restrict__ degu,
                                             unsigned int* __restrict__ base,
                                             unsigned int* __restrict__ pof) {
    __shared__ unsigned int dg[U_N];    // degrees -> exclusive base
    __shared__ unsigned int wt[4];
    __shared__ unsigned int ps[8][32];
    int tid = threadIdx.x;
    int wave = tid >> 6, lane = tid & 63;
    for (int t = tid; t < U_N; t += 256) dg[t] = degu[t];
    __syncthreads();
    unsigned int loc[8];
    unsigned int s = 0;
#pragma unroll
    for (int j = 0; j < 8; ++j) { loc[j] = dg[tid * 8 + j]; s += loc[j]; }
    unsigned int inc = s;
#pragma unroll
    for (int off = 1; off < 64; off <<= 1) {
        unsigned int o = __shfl_up(inc, off);
        if (lane >= off) inc += o;
    }
    if (lane == 63) wt[wave] = inc;
    __syncthreads();
    unsigned int woff = 0;
#pragma unroll
    for (int w = 0; w < 4; ++w) woff += (w < wave) ? wt[w] : 0u;
    unsigned int ex = woff + inc - s;
    __syncthreads();
    {
        unsigned int run = ex;
#pragma unroll
        for (int j = 0; j < 8; ++j) { unsigned int v = loc[j]; dg[tid * 8 + j] = run; run += v; }
    }
    __syncthreads();
    int c = tid >> 5, l = tid & 31;
    int u = blockIdx.x * 32 + l;
    if (c == 0) base[u] = dg[u];
    unsigned int v32[32];
    unsigned int sum = 0;
#pragma unroll
    for (int k = 0; k < 32; ++k) {
        v32[k] = pu[(size_t)(c * 32 + k) * U_N + u];
        sum += v32[k];
    }
    ps[c][l] = sum;
    __syncthreads();
    unsigned int run = dg[u];
#pragma unroll
    for (int c2 = 0; c2 < 8; ++c2) run += (c2 < c) ? ps[c2][l] : 0u;
#pragma unroll
    for (int k = 0; k < 32; ++k) {
        pof[(size_t)(c * 32 + k) * U_N + u] = run;
        run += v32[k];
    }
}

// ---------------- fused: esort (blocks 0-255) | projections (blocks 256+) ---
// esort traversal must match k_deg_part exactly (same block/stride/tail map).
#define NPROJ (((U_N + I_N) * H_N) / 256)   // 2304 proj blocks
__global__ __launch_bounds__(256) void k_pe(const int* __restrict__ src,
                                            const int* __restrict__ dst, int E,
                                            const unsigned int* __restrict__ pof,
                                            unsigned short* __restrict__ sorted,
                                            const float* __restrict__ x,
                                            const float* __restrict__ w1,
                                            const float* __restrict__ b1,
                                            const float* __restrict__ du,
                                            const float* __restrict__ di,
                                            float* __restrict__ Pu,
                                            float* __restrict__ Pi) {
    __shared__ unsigned int cur[U_N];   // 8 KB (esort blocks only)
    int tid = threadIdx.x;
    int bid = blockIdx.x;
    if (bid < NB_DEG) {
        const unsigned int* p = pof + (size_t)bid * U_N;
        for (int t = tid; t < U_N; t += 256) cur[t] = p[t];
        __syncthreads();
        const int4* s4 = (const int4*)src;
        const int4* d4 = (const int4*)dst;
        int nv = E >> 2;
        for (int v = bid * 256 + tid; v < nv; v += NB_DEG * 256) {
            int4 u = s4[v], i = d4[v];
            sorted[atomicAdd(&cur[u.x], 1u)] = (unsigned short)i.x;
            sorted[atomicAdd(&cur[u.y], 1u)] = (unsigned short)i.y;
            sorted[atomicAdd(&cur[u.z], 1u)] = (unsigned short)i.z;
            sorted[atomicAdd(&cur[u.w], 1u)] = (unsigned short)i.w;
        }
        if (bid == 0) {
            int e = nv * 4 + tid;
            if (e < E)
                sorted[atomicAdd(&cur[src[e]], 1u)] = (unsigned short)dst[e];
        }
    } else {
        int t = (bid - NB_DEG) * 256 + tid;
        if (t < U_N * H_N) {
            int u = t >> 5, j = t & 31;
            const float* xr = x + (size_t)u * F_N;
            const float* wr = w1 + (size_t)j * (2 * F_N + 2);
            float acc = b1[j] + du[u] * wr[64];
#pragma unroll
            for (int f = 0; f < F_N; ++f) acc = fmaf(xr[f], wr[f], acc);
            Pu[t] = acc;
        } else {
            int t2 = t - U_N * H_N;
            int i = t2 >> 5, j = t2 & 31;
            const float* xr = x + (size_t)(U_N + i) * F_N;
            const float* wr = w1 + (size_t)j * (2 * F_N + 2) + 65;
            float acc = di[i] * wr[64];  // w1[j][129]
#pragma unroll
            for (int f = 0; f < F_N; ++f) acc = fmaf(xr[f], wr[f], acc);
            Pi[t2] = acc;
        }
    }
}

// ---------------- per-user: weights + f32 LDS row -> fp8 row + exact diag ---
__global__ __launch_bounds__(256) void k_edge2(const unsigned short* __restrict__ sorted,
                                               const unsigned int* __restrict__ base,
                                               const unsigned int* __restrict__ degu,
                                               const float* __restrict__ Pu,
                                               const float* __restrict__ Pi,
                                               const float* __restrict__ w2,
                                               const float* __restrict__ b2,
                                               unsigned int* __restrict__ A8w,
                                               float* __restrict__ diag) {
    __shared__ float hrow[I_N];   // 64 KB
    __shared__ float red[256];
    int u = blockIdx.x, tid = threadIdx.x;
    float4* h4 = (float4*)hrow;
    float4 z4 = {0.f, 0.f, 0.f, 0.f};
#pragma unroll
    for (int j = 0; j < 16; ++j) h4[tid + j * 256] = z4;

    float pur[H_N], w2r[H_N];
#pragma unroll
    for (int j = 0; j < H_N; ++j) pur[j] = Pu[(size_t)u * H_N + j];
#pragma unroll
    for (int j = 0; j < H_N; ++j) w2r[j] = w2[j];
    float bb = b2[0];
    __syncthreads();

    int nb = (int)base[u], d = (int)degu[u];
    for (int k = tid; k < d; k += 256) {
        int i = (int)sorted[nb + k];
        const float4* pi4 = (const float4*)(Pi + (size_t)i * H_N);
        float acc = bb;
#pragma unroll
        for (int q = 0; q < H_N / 4; ++q) {
            float4 b = pi4[q];
            acc = fmaf(fmaxf(pur[4 * q + 0] + b.x, 0.f), w2r[4 * q + 0], acc);
            acc = fmaf(fmaxf(pur[4 * q + 1] + b.y, 0.f), w2r[4 * q + 1], acc);
            acc = fmaf(fmaxf(pur[4 * q + 2] + b.z, 0.f), w2r[4 * q + 2], acc);
            acc = fmaf(fmaxf(pur[4 * q + 3] + b.w, 0.f), w2r[4 * q + 3], acc);
        }
        float wgt = 1.0f / (1.0f + expf(-acc));
        atomicAdd(&hrow[i], wgt);   // ds_add_f32
    }
    __syncthreads();

    // flush fp8 row (4 vals/word, RNE) + exact fp32 sum of squares (diagonal)
    unsigned int* row = A8w + (size_t)u * (I_N / 4);
    float ss = 0.f;
#pragma unroll
    for (int j = 0; j < 16; ++j) {
        int w = tid + j * 256;
        float4 a = h4[w];
        int v = __builtin_amdgcn_cvt_pk_fp8_f32(a.x, a.y, 0, false);
        v = __builtin_amdgcn_cvt_pk_fp8_f32(a.z, a.w, v, true);
        row[w] = (unsigned int)v;
        ss = fmaf(a.x, a.x, ss); ss = fmaf(a.y, a.y, ss);
        ss = fmaf(a.z, a.z, ss); ss = fmaf(a.w, a.w, ss);
    }
    red[tid] = ss;
    __syncthreads();
#pragma unroll
    for (int s = 128; s > 0; s >>= 1) {
        if (tid < s) red[tid] += red[tid + s];
        __syncthreads();
    }
    if (tid == 0) diag[u] = red[0];
}

// ---------------- C = A * A^T via fp8 MFMA, XOR-swizzled LDS, XCD chunks ----
// Round-13 measured best (88 us): BKB=128, KSPLIT=4. Structural variants all
// regressed: +dbuf (r12, +6us), KSPLIT=8 (r14, +6us), BKB=256 (r15, +7us).
#define BM 128
#define BKB 128                         // fp8 bytes per k-tile
#define NBLK (U_N / BM)                 // 16
#define NPAIR (NBLK * (NBLK + 1) / 2)   // 136
#define KSPLIT 4
#define KCH (KDIM / KSPLIT)             // 4096

__global__ __launch_bounds__(256) void k_syrk(const unsigned char* __restrict__ A8,
                                              float* __restrict__ C) {
    __shared__ unsigned char As[BM * BKB];   // 16 KB
    __shared__ unsigned char Bs[BM * BKB];   // 16 KB

    int k0 = blockIdx.x * KCH;          // k-chunk (XCD-locality)
    int p = blockIdx.y;                 // pair index -> (bi, bj), bi <= bj
    int bi = 0, rem = p;
    while (rem >= NBLK - bi) { rem -= NBLK - bi; ++bi; }
    int bj = bi + rem;
    int diagp = (bi == bj);

    int tid = threadIdx.x;
    int wave = tid >> 6, lane = tid & 63;

    // staging: wave w fills rows [w*32,w*32+32), 4 calls of 8 rows each.
    // lane l -> LDS (row l>>3, chunk pos l&7); global chunk = (l&7)^(l>>3).
    int srow = wave * 32 + (lane >> 3);
    int scol = ((lane & 7) ^ (lane >> 3)) * 16;   // bytes
    const unsigned char* Ag = A8 + (size_t)(bi * BM + srow) * KDIM + k0 + scol;
    const unsigned char* Bg = A8 + (size_t)(bj * BM + srow) * KDIM + k0 + scol;
    unsigned char* lA = As + (wave * 32) * BKB;   // wave-uniform bases
    unsigned char* lB = Bs + (wave * 32) * BKB;

    // MFMA coords: 4 waves, each a 64x64 quadrant (4x4 of 16x16 tiles)
    int wm = wave >> 1, wn = wave & 1;
    int lm = lane & 15, lq = lane >> 4;
    int lm7 = lm & 7;
    const unsigned char* bTile = diagp ? As : Bs;

    f32x4 acc[4][4];
#pragma unroll
    for (int m = 0; m < 4; ++m)
#pragma unroll
        for (int n = 0; n < 4; ++n) acc[m][n] = (f32x4){0.f, 0.f, 0.f, 0.f};

    for (int kt = 0; kt < KCH; kt += BKB) {
        __syncthreads();              // previous tile fully consumed
#pragma unroll
        for (int j = 0; j < 4; ++j)
            gload16(Ag + kt + (size_t)(j * 8) * KDIM, lA + j * 8 * BKB);
        if (!diagp) {
#pragma unroll
            for (int j = 0; j < 4; ++j)
                gload16(Bg + kt + (size_t)(j * 8) * KDIM, lB + j * 8 * BKB);
        }
        __syncthreads();              // vmcnt(0) drain -> tile ready

#pragma unroll
        for (int s = 0; s < 4; ++s) {   // 4 k-steps of 32 within BKB=128
            // canonical chunk c = s*2 + (lq>>1); half = lq&1
            int off = ((s * 2 + (lq >> 1)) ^ lm7) * 16 + (lq & 1) * 8;
            long av[4], bv[4];
#pragma unroll
            for (int m = 0; m < 4; ++m)
                av[m] = *(const long*)(As + (wm * 64 + m * 16 + lm) * BKB + off);
#pragma unroll
            for (int n = 0; n < 4; ++n)
                bv[n] = *(const long*)(bTile + (wn * 64 + n * 16 + lm) * BKB + off);
#pragma unroll
            for (int m = 0; m < 4; ++m)
#pragma unroll
                for (int n = 0; n < 4; ++n)
                    acc[m][n] = __builtin_amdgcn_mfma_f32_16x16x32_fp8_fp8(
                        av[m], bv[n], acc[m][n], 0, 0, 0);
        }
    }

    // epilogue: C/D layout col=lane&15, row=lq*4+reg (m89-verified).
    // Upper-triangle tile only; k_mirror fills the lower triangle.
#pragma unroll
    for (int m = 0; m < 4; ++m) {
        int rb = bi * BM + wm * 64 + m * 16 + lq * 4;
#pragma unroll
        for (int n = 0; n < 4; ++n) {
            int c = bj * BM + wn * 64 + n * 16 + lm;
            f32x4 v = acc[m][n];
#pragma unroll
            for (int g = 0; g < 4; ++g)
                atomicAdd(&C[(size_t)(rb + g) * U_N + c], v[g]);
        }
    }
}

// ---------------- mirror lower triangle from upper ----------------
__global__ __launch_bounds__(256) void k_mirror(float* __restrict__ C) {
    __shared__ float T[64][65];
    int tr = blockIdx.x, tc = blockIdx.y;   // dest 64-tile coords
    if ((tr >> 1) <= (tc >> 1)) return;     // keep only 128-block lower
    int lane = threadIdx.x & 63;
    int w = threadIdx.x >> 6;               // 0..3
#pragma unroll
    for (int s = 0; s < 16; ++s) {
        int r = s * 4 + w;
        T[r][lane] = C[(size_t)(tc * 64 + r) * U_N + tr * 64 + lane];
    }
    __syncthreads();
#pragma unroll
    for (int s = 0; s < 16; ++s) {
        int r = s * 4 + w;
        C[(size_t)(tr * 64 + r) * U_N + tc * 64 + lane] = T[lane][r];
    }
}

// ---------------- top-3 per row (scaled, exact diag) + fused scatter --------
__device__ __forceinline__ bool better(float va, int ia, float vb, int ib) {
    return (va > vb) || (va == vb && ia < ib);
}
__device__ __forceinline__ void ins3(float v, int i, float& v0, int& i0,
                                     float& v1, int& i1, float& v2, int& i2) {
    if (better(v, i, v0, i0)) { v2 = v1; i2 = i1; v1 = v0; i1 = i0; v0 = v; i0 = i; }
    else if (better(v, i, v1, i1)) { v2 = v1; i2 = i1; v1 = v; i1 = i; }
    else if (better(v, i, v2, i2)) { v2 = v; i2 = i; }
}

__global__ __launch_bounds__(256) void k_topk(const float* __restrict__ C,
                                              const float* __restrict__ Dh,
                                              const float* __restrict__ diag,
                                              float* __restrict__ out) {
    int wave = threadIdx.x >> 6, lane = threadIdx.x & 63;
    int r = blockIdx.x * 4 + wave;                // one wave per row
    float dr = Dh[r];
    float dex = diag[r] * dr * dr;                // exact C[r,r]*d_u[r]
    float dval = (dex > 0.f) ? dex : NEGV;
    const float4* row = (const float4*)(C + (size_t)r * U_N);
    const float4* dh4 = (const float4*)Dh;
    float v0 = NEGV, v1 = NEGV, v2 = NEGV;
    int i0 = 0x7fffffff, i1 = 0x7fffffff, i2 = 0x7fffffff;
    int qr = r >> 2;
    for (int q = lane; q < U_N / 4; q += 64) {
        float4 cv = row[q];
        float4 dv = dh4[q];
        int c = q * 4;
        float x0 = (cv.x > 0.f) ? cv.x * dr * dv.x : NEGV;
        float x1 = (cv.y > 0.f) ? cv.y * dr * dv.y : NEGV;
        float x2 = (cv.z > 0.f) ? cv.z * dr * dv.z : NEGV;
        float x3 = (cv.w > 0.f) ? cv.w * dr * dv.w : NEGV;
        if (q == qr) {                       // substitute exact diagonal
            int j = r & 3;
            if (j == 0) x0 = dval; else if (j == 1) x1 = dval;
            else if (j == 2) x2 = dval; else x3 = dval;
        }
        if (better(x0, c + 0, v2, i2)) ins3(x0, c + 0, v0, i0, v1, i1, v2, i2);
        if (better(x1, c + 1, v2, i2)) ins3(x1, c + 1, v0, i0, v1, i1, v2, i2);
        if (better(x2, c + 2, v2, i2)) ins3(x2, c + 2, v0, i0, v1, i1, v2, i2);
        if (better(x3, c + 3, v2, i2)) ins3(x3, c + 3, v0, i0, v1, i1, v2, i2);
    }
#pragma unroll
    for (int off = 1; off < 64; off <<= 1) {
        float ov0 = __shfl_xor(v0, off), ov1 = __shfl_xor(v1, off), ov2 = __shfl_xor(v2, off);
        int oi0 = __shfl_xor(i0, off), oi1 = __shfl_xor(i1, off), oi2 = __shfl_xor(i2, off);
        ins3(ov0, oi0, v0, i0, v1, i1, v2, i2);
        ins3(ov1, oi1, v0, i0, v1, i1, v2, i2);
        ins3(ov2, oi2, v0, i0, v1, i1, v2, i2);
    }
    if (lane == 0) {                 // fused scatter: S = T + T^T
        float vs[3] = {v0, v1, v2};
        int is[3] = {i0, i1, i2};
#pragma unroll
        for (int k = 0; k < 3; ++k) {
            if (vs[k] > 0.f) {
                atomicAdd(&out[(size_t)r * U_N + is[k]], 0.5f * vs[k]);
                atomicAdd(&out[(size_t)is[k] * U_N + r], 0.5f * vs[k]);
            }
        }
    }
}

extern "C" void kernel_launch(void* const* d_in, const int* in_sizes, int n_in,
                              void* d_out, int out_size, void* d_ws, size_t ws_size,
                              hipStream_t stream) {
    const float* x  = (const float*)d_in[0];
    const float* w1 = (const float*)d_in[1];
    const float* b1 = (const float*)d_in[2];
    const float* w2 = (const float*)d_in[3];
    const float* b2 = (const float*)d_in[4];
    const int* esrc = (const int*)d_in[5];
    const int* edst = (const int*)d_in[6];
    int E = in_sizes[5];
    float* out = (float*)d_out;

    // workspace layout (~65 MB)
    unsigned char* A8 = (unsigned char*)d_ws;             // U*I fp8 (32 MiB)
    float* C    = (float*)(A8 + (size_t)U_N * I_N);       // U*U (16 MiB)
    float* Pu   = C + (size_t)U_N * U_N;                  // U*H
    float* Pi   = Pu + (size_t)U_N * H_N;                 // I*H (2 MiB)
    unsigned int* pu  = (unsigned int*)(Pi + (size_t)I_N * H_N);  // NB*U (2 MiB)
    unsigned int* pi2 = pu + (size_t)NB_DEG * U_N;        // NB*I/2 (8 MiB)
    unsigned int* pof = pi2 + (size_t)NB_DEG * (I_N / 2); // NB*U (2 MiB)
    unsigned int* degu = pof + (size_t)NB_DEG * U_N;      // U
    unsigned int* base = degu + U_N;                      // U
    float* du   = (float*)(base + U_N);                   // U
    float* di   = du + U_N;                               // I
    float* Dh   = di + I_N;                               // U
    float* diag = Dh + U_N;                               // U
    unsigned short* sorted = (unsigned short*)(diag + U_N);   // E u16 (2 MiB)

    k_deg_part<<<NB_DEG, 256, 0, stream>>>(esrc, edst, E, pu, pi2, C, out);
    k_node2<<<(U_N + I_N / 2) / 32, 256, 0, stream>>>(pu, pi2, du, di, Dh,
                                                      out + (size_t)U_N * U_N, degu);
    k_pof<<<U_N / 32, 256, 0, stream>>>(pu, degu, base, pof);
    k_pe<<<NB_DEG + NPROJ, 256, 0, stream>>>(esrc, edst, E, pof, sorted,
                                             x, w1, b1, du, di, Pu, Pi);
    k_edge2<<<U_N, 256, 0, stream>>>(sorted, base, degu, Pu, Pi, w2, b2,
                                     (unsigned int*)A8, diag);
    k_syrk<<<dim3(KSPLIT, NPAIR), 256, 0, stream>>>(A8, C);
    k_mirror<<<dim3(U_N / 64, U_N / 64), 256, 0, stream>>>(C);
    k_topk<<<U_N / 4, 256, 0, stream>>>(C, Dh, diag, out);
}